// Round 17
// baseline (240.836 us; speedup 1.0000x reference)
//
#include <hip/hip_runtime.h>
#include <hip/hip_bf16.h>
#include <stdint.h>

typedef unsigned short u16;
typedef __attribute__((ext_vector_type(8))) short short8;
typedef __attribute__((ext_vector_type(4))) short short4a;
typedef __attribute__((ext_vector_type(4))) float f32x4;

__device__ __forceinline__ float bf2f(u16 b){ union {unsigned u; float f;} v; v.u = ((unsigned)b)<<16; return v.f; }
__device__ __forceinline__ u16 f2bf(float f){ union {unsigned u; float f;} v; v.f = f; unsigned r = v.u + 0x7FFF + ((v.u>>16)&1); return (u16)(r>>16); }

// ---------------- bpack element index for (s, mat, w, v)
__device__ __forceinline__ size_t bpidx(int s, int mat, int w, int v){
  return ((size_t)(((s*2+mat)*8 + (v>>5))*16 + (w>>4)))*512 + (((v>>3)&3)*16 + (w&15))*8 + (v&7);
}

// ---------------- adaptive adjacency (blocks 0..255) + weight prep (blocks 256..343)
__global__ __launch_bounds__(256) void k_adpw(const float* __restrict__ nv1, const float* __restrict__ nv2,
                                              float* __restrict__ adp,
                                              const float* __restrict__ wm1, const float* __restrict__ wm2,
                                              const float* __restrict__ wf1, const float* __restrict__ wg1,
                                              const float* __restrict__ wf2, const float* __restrict__ wg2,
                                              u16* __restrict__ whi, u16* __restrict__ wlo,
                                              u16* __restrict__ wcp){
  int bid = blockIdx.x;
  if(bid < 256){
    int row = bid; int j = threadIdx.x;
    float s = 0.f;
    #pragma unroll
    for(int k=0;k<10;k++) s = fmaf(nv1[row*10+k], nv2[k*256+j], s);
    s = s > 0.f ? s : 0.f;
    float val = (s == 0.f) ? -1e10f : s;
    __shared__ float red[256];
    red[j] = val; __syncthreads();
    for(int off=128; off>0; off>>=1){ if(j<off) red[j] = fmaxf(red[j], red[j+off]); __syncthreads(); }
    float mx = red[0]; __syncthreads();
    float e = __expf(val - mx);
    red[j] = e; __syncthreads();
    for(int off=128; off>0; off>>=1){ if(j<off) red[j] += red[j+off]; __syncthreads(); }
    adp[row*256+j] = e / red[0];
  } else {
    int idx = (bid-256)*256 + threadIdx.x;
    if(idx < 14336){
      float w = (idx < 7168) ? wm1[idx] : wm2[idx-7168];
      u16 hh = f2bf(w);
      whi[idx] = hh;
      wlo[idx] = f2bf(w - bf2f(hh));
    } else if(idx < 22528){
      int e = idx - 14336;
      int blk = e >> 12; int rem = e & 4095;
      int row = rem >> 6; int kk = rem & 63;
      int tap = kk >> 5; int i = kk & 31; int o = row & 31;
      const float* wsrc = blk ? (row<32 ? wf2 : wg2) : (row<32 ? wf1 : wg1);
      float w = wsrc[(o*32+i)*2 + tap];
      u16 hh = f2bf(w);
      wcp[blk*8192 + 0    + rem] = hh;
      wcp[blk*8192 + 4096 + rem] = f2bf(w - bf2f(hh));
    }
  }
}

// ---------------- badj[s][w][v] = src_s[v][w]; also writes bpack mat=0 entries
__global__ __launch_bounds__(256) void k_badj(const float* __restrict__ s0, const float* __restrict__ s1,
                                              const float* __restrict__ adp, u16* __restrict__ badj,
                                              u16* __restrict__ bpack){
  int s = blockIdx.x >> 8; int w = blockIdx.x & 255; int v = threadIdx.x;
  const float* src = s==0 ? s0 : (s==1 ? s1 : adp);
  u16 val = f2bf(src[v*256 + w]);
  badj[(s<<16) + (w<<8) + v] = val;
  bpack[bpidx(s, 0, w, v)] = val;
}

// ---------------- x [b][c][n][t] f32 -> xT [b][t][c][n] bf16
__global__ __launch_bounds__(256) void k_tin(const float* __restrict__ x, u16* __restrict__ xT){
  int tile = blockIdx.x & 15; int slice = blockIdx.x >> 4;
  int b = slice >> 5, c = slice & 31;
  int tn0 = (tile & 3) * 64;
  int tt0 = (tile >> 2) * 64;
  const float* src = x + (size_t)slice*65536;
  __shared__ float l[64][65];
  int cc = threadIdx.x & 63, r0 = threadIdx.x >> 6;
  #pragma unroll
  for(int k=0;k<16;k++){ int r = r0 + 4*k;
    l[r][cc] = src[(size_t)(tn0 + r)*256 + tt0 + cc];
  }
  __syncthreads();
  #pragma unroll
  for(int k=0;k<16;k++){ int r = r0 + 4*k;
    xT[(((size_t)b*256 + (tt0+r))*32 + c)*256 + tn0 + cc] = f2bf(l[cc][r]);
  }
}

// ---------------- A^2: reads badj (staged), writes results DIRECTLY in bpack mat=1 layout
__global__ __launch_bounds__(256) void k_asq(const u16* __restrict__ badj,
                                             const float* __restrict__ s0, const float* __restrict__ s1,
                                             const float* __restrict__ adp, u16* __restrict__ bpack){
  __shared__ __align__(16) u16 lds[16384];
  int tid = threadIdx.x, bid = blockIdx.x;
  int s = bid >> 2, rt = bid & 3;
  int w0 = rt << 6;
  const u16* T = badj + (s<<16);
  const float* S = s==0 ? s0 : (s==1 ? s1 : adp);
  #pragma unroll
  for(int i=0;i<8;i++){
    int off = i*4096 + tid*16;
    int row = off >> 9;
    int P = (off >> 4) & 31;
    int L = (P & 16) | ((P & 15) ^ (row & 15));
    short8 v = *(const short8*)((const char*)T + (size_t)(w0 + row)*512 + L*16);
    *(short8*)((char*)lds + off) = v;
  }
  __syncthreads();
  int lane = tid & 63, wave = tid >> 6;
  int wr = (wave >> 1) << 5, wc = (wave & 1) << 7;
  f32x4 acc[2][8];
  #pragma unroll
  for(int a=0;a<2;a++)
    #pragma unroll
    for(int q=0;q<8;q++) acc[a][q] = {0.f,0.f,0.f,0.f};
  for(int ks=0; ks<8; ks++){
    short8 afr[2], bfr[8];
    #pragma unroll
    for(int mf=0; mf<2; mf++){
      int row = wr + mf*16 + (lane & 15);
      int L = ks*4 + (lane >> 4);
      int P = (L & 16) | ((L & 15) ^ (row & 15));
      afr[mf] = *(const short8*)&lds[row*256 + P*8];
    }
    #pragma unroll
    for(int nf=0; nf<8; nf++){
      int col = wc + nf*16 + (lane & 15);
      const float* src = S + (size_t)col*256 + ks*32 + (lane>>4)*8;
      #pragma unroll
      for(int jj=0;jj<8;jj++) bfr[nf][jj] = (short)f2bf(src[jj]);
    }
    #pragma unroll
    for(int mf=0;mf<2;mf++)
      #pragma unroll
      for(int nf=0;nf<8;nf++)
        acc[mf][nf] = __builtin_amdgcn_mfma_f32_16x16x32_bf16(afr[mf], bfr[nf], acc[mf][nf], 0,0,0);
  }
  #pragma unroll
  for(int mf=0;mf<2;mf++)
    #pragma unroll
    for(int nf=0;nf<8;nf++)
      #pragma unroll
      for(int rr=0;rr<4;rr++){
        int w = w0 + wr + mf*16 + (lane>>4)*4 + rr;
        int v = wc + nf*16 + (lane&15);
        bpack[bpidx(s, 1, w, v)] = f2bf(acc[mf][nf][rr]);
      }
}

// ---------------- MFMA gated conv (+bias, sigmoid gate)
template<int HILO>
__global__ __launch_bounds__(256) void k_cv(const u16* __restrict__ X0, const u16* __restrict__ X1,
                                            const u16* __restrict__ wcp, int blk, int dil,
                                            const float* __restrict__ bfv, const float* __restrict__ bgv,
                                            u16* __restrict__ outh){
  __shared__ __align__(16) u16 pl[(1+HILO)*2*8192];
  const int NPART = 1+HILO;
  int tid = threadIdx.x, bid = blockIdx.x;
  int b = bid >> 8, t = bid & 255;
  size_t base_cur = ((size_t)(b*256 + t))*8192;
  const u16* Xs[2] = {X0, X1};
  #pragma unroll
  for(int part=0; part<NPART; part++){
    #pragma unroll
    for(int tap=0; tap<2; tap++){
      bool valid = (tap==1) || (t >= dil);
      const u16* src = Xs[part] + base_cur - (tap==0 ? (size_t)dil*8192 : 0);
      char* pb = (char*)pl + (tap*NPART + part)*16384;
      #pragma unroll
      for(int it=0; it<4; it++){
        int off = it*4096 + tid*16;
        int c = off >> 9;
        int byte = off & 511;
        short8 v = {0,0,0,0,0,0,0,0};
        if(valid) v = *(const short8*)(src + (off>>1));
        *(short8*)(pb + c*512 + (byte ^ ((c&24)<<2))) = v;
      }
    }
  }
  int lane = tid & 63, wave = tid >> 6;
  const u16* wb = wcp + blk*8192;
  short8 wfr[4][2][2];
  #pragma unroll
  for(int ot=0;ot<4;ot++)
    #pragma unroll
    for(int ks=0;ks<2;ks++)
      #pragma unroll
      for(int p=0;p<2;p++)
        wfr[ot][ks][p] = *(const short8*)(wb + p*4096 + (ot*16 + (lane&15))*64 + ks*32 + (lane>>4)*8);
  __syncthreads();

  f32x4 acc[4][4];
  #pragma unroll
  for(int a=0;a<4;a++)
    #pragma unroll
    for(int q=0;q<4;q++) acc[a][q] = {0.f,0.f,0.f,0.f};
  int nbase = wave << 6;
  #pragma unroll
  for(int nf=0; nf<4; nf++){
    int n = nbase + nf*16 + (lane & 15);
    #pragma unroll
    for(int ks=0; ks<2; ks++){
      short8 xv[NPART];
      #pragma unroll
      for(int p=0;p<NPART;p++){
        char* pb = (char*)pl + (ks*NPART + p)*16384;
        short8 v;
        #pragma unroll
        for(int jj=0;jj<8;jj++){
          int c = ((lane>>4)<<3) + jj;
          v[jj] = *(const short*)(pb + c*512 + ((n*2) ^ ((c&24)<<2)));
        }
        xv[p] = v;
      }
      #pragma unroll
      for(int ot=0; ot<4; ot++){
        acc[ot][nf] = __builtin_amdgcn_mfma_f32_16x16x32_bf16(wfr[ot][ks][0], xv[0], acc[ot][nf], 0,0,0);
        acc[ot][nf] = __builtin_amdgcn_mfma_f32_16x16x32_bf16(wfr[ot][ks][1], xv[0], acc[ot][nf], 0,0,0);
        if(HILO)
          acc[ot][nf] = __builtin_amdgcn_mfma_f32_16x16x32_bf16(wfr[ot][ks][0], xv[HILO], acc[ot][nf], 0,0,0);
      }
    }
  }
  u16* ob = outh + base_cur;
  #pragma unroll
  for(int ot=0; ot<2; ot++)
    #pragma unroll
    for(int nf=0; nf<4; nf++)
      #pragma unroll
      for(int rr=0; rr<4; rr++){
        int o = ot*16 + (lane>>4)*4 + rr;
        int n = nbase + nf*16 + (lane&15);
        float fv = acc[ot][nf][rr] + bfv[o];
        float gv = acc[ot+2][nf][rr] + bgv[o];
        ob[(size_t)o*256 + n] = f2bf(fv / (1.f + __expf(-gv)));
      }
}

// ---------------- gather helpers
__device__ __forceinline__ short8 gathA(const u16* TB, int n, int khi){
  short8 f; int Lc = n >> 3; int bb = (n & 7)*2;
  #pragma unroll
  for(int j=0;j<8;j++){
    int c = khi*8 + j;
    int P = (Lc & 16) | ((Lc & 15) ^ (c & 15));
    f[j] = (short)*(const u16*)((const char*)TB + c*512 + P*16 + bb);
  }
  return f;
}
__device__ __forceinline__ short8 gathY(const char* myY, int nl, int khi){
  const char* rp = myY + nl*72 + khi*16;
  short4a g0 = *(const short4a*)rp;
  short4a g1 = *(const short4a*)(rp + 8);
  return (short8){g0[0],g0[1],g0[2],g0[3],g1[0],g1[1],g1[2],g1[3]};
}

#define MF(A,B,C) __builtin_amdgcn_mfma_f32_16x16x32_bf16((A),(B),(C),0,0,0)

// ================ k_fuse2: NT=2 variant (round-15 code, attribute-only change) ================
#define LBP(BASE,K2,FC) (*(const short8*)((BASE) + (((K2)*16 + cg0 + (FC))<<9) + (lane<<3)))
#define AFU(U,MFI,KS) (*(const short8*)&lA[U][((MFI)*16 + nlo)*256 + ((((KS)*4+khi)&16)|((((KS)*4+khi)&15)^(((MFI)*16+nlo)&15)))*8])
#define STEP(KS,BA,BB) \
  { short8 a00=AFU(0,0,KS), a01=AFU(0,1,KS), a10=AFU(1,0,KS), a11=AFU(1,1,KS); \
    hA00=MF(a00,BA,hA00); hA01=MF(a00,BB,hA01); hA10=MF(a01,BA,hA10); hA11=MF(a01,BB,hA11); \
    hB00=MF(a10,BA,hB00); hB01=MF(a10,BB,hB01); hB10=MF(a11,BA,hB10); hB11=MF(a11,BB,hB11); \
    if((KS)<6){ BA = LBP(bpv,(KS)+2,0); BB = LBP(bpv,(KS)+2,1); } \
    else if(v<5){ BA = LBP(bpn,(KS)-6,0); BB = LBP(bpn,(KS)-6,1); } }
#define MIXU(F0,F1,O00,O01,O10,O11) \
  { short8 f0=(F0), f1=(F1); \
    O00=MF(wh0,f0,O00); O00=MF(wl0,f0,O00); O10=MF(wh1,f0,O10); O10=MF(wl1,f0,O10); \
    O01=MF(wh0,f1,O01); O01=MF(wl0,f1,O01); O11=MF(wh1,f1,O11); O11=MF(wl1,f1,O11); }
__global__ __attribute__((amdgpu_flat_work_group_size(256,256), amdgpu_waves_per_eu(3,3)))
void k_fuse2(const u16* __restrict__ X,
             const u16* __restrict__ bpack,
             const u16* __restrict__ WH, const u16* __restrict__ WL,
             const float* __restrict__ bm,
             u16* __restrict__ mbh, u16* __restrict__ mbl){
  __shared__ __align__(16) u16 lA[2][8192];    // 32 KB
  __shared__ __align__(16) char lYT[2][9216];  // 18 KB
  int tid = threadIdx.x, bid = blockIdx.x;
  int ch = bid & 1;
  int tp = (bid >> 1) & 127;
  int b  = bid >> 8;
  size_t cb0 = ((size_t)b*256 + tp) * 8192;
  size_t cb1 = cb0 + (size_t)128*8192;
  #pragma unroll
  for(int u=0;u<2;u++){
    const char* Xb = (const char*)(X + (u ? cb1 : cb0));
    #pragma unroll
    for(int i=0;i<4;i++){
      int off = i*4096 + tid*16;
      int row = off >> 9;
      int P = (off >> 4) & 31;
      int L = (P & 16) | ((P & 15) ^ (row & 15));
      short8 v = *(const short8*)(Xb + (size_t)row*512 + L*16);
      *(short8*)((char*)&lA[u][0] + off) = v;
    }
  }
  __syncthreads();
  int lane = tid & 63, wave = tid >> 6;
  int nlo = lane & 15, khi = lane >> 4;
  int cg0 = ch*8 + wave*2;
  char* myY0 = &lYT[0][0] + wave*2304;
  char* myY1 = &lYT[1][0] + wave*2304;

  f32x4 oA00={0,0,0,0}, oA01=oA00, oA10=oA00, oA11=oA00;
  f32x4 oB00=oA00, oB01=oA00, oB10=oA00, oB11=oA00;

  const u16* bpv = bpack;
  short8 B0A = LBP(bpv,0,0), B0B = LBP(bpv,0,1);
  short8 B1A = LBP(bpv,1,0), B1B = LBP(bpv,1,1);

  {
    int wiA = nlo*224 + khi*8;
    short8 wh0 = *(const short8*)(WH + wiA);
    short8 wl0 = *(const short8*)(WL + wiA);
    short8 wh1 = *(const short8*)(WH + wiA + 3584);
    short8 wl1 = *(const short8*)(WL + wiA + 3584);
    int n0 = (ch*8 + wave*2)*16 + nlo;
    MIXU(gathA(&lA[0][0], n0, khi), gathA(&lA[0][0], n0+16, khi), oA00, oA01, oA10, oA11);
    MIXU(gathA(&lA[1][0], n0, khi), gathA(&lA[1][0], n0+16, khi), oB00, oB01, oB10, oB11);
  }

  #pragma unroll 1
  for(int v=0; v<6; ++v){
    const u16* bpn = bpv + 65536;
    f32x4 hA00={0,0,0,0}, hA01=hA00, hA10=hA00, hA11=hA00;
    f32x4 hB00=hA00, hB01=hA00, hB10=hA00, hB11=hA00;
    STEP(0,B0A,B0B)
    STEP(1,B1A,B1B)
    STEP(2,B0A,B0B)
    STEP(3,B1A,B1B)
    STEP(4,B0A,B0B)
    STEP(5,B1A,B1B)
    STEP(6,B0A,B0B)
    STEP(7,B1A,B1B)
    #pragma unroll
    for(int mf=0;mf<2;mf++)
      #pragma unroll
      for(int nf=0;nf<2;nf++){
        f32x4 hv = mf==0 ? (nf==0?hA00:hA01) : (nf==0?hA10:hA11);
        short4a wv;
        wv[0]=(short)f2bf(hv[0]); wv[1]=(short)f2bf(hv[1]);
        wv[2]=(short)f2bf(hv[2]); wv[3]=(short)f2bf(hv[3]);
        *(short4a*)(myY0 + (nf*16+nlo)*72 + mf*32 + khi*8) = wv;
        f32x4 gv = mf==0 ? (nf==0?hB00:hB01) : (nf==0?hB10:hB11);
        short4a xv;
        xv[0]=(short)f2bf(gv[0]); xv[1]=(short)f2bf(gv[1]);
        xv[2]=(short)f2bf(gv[2]); xv[3]=(short)f2bf(gv[3]);
        *(short4a*)(myY1 + (nf*16+nlo)*72 + mf*32 + khi*8) = xv;
      }
    {
      int wiA = nlo*224 + (v+1)*32 + khi*8;
      short8 wh0 = *(const short8*)(WH + wiA);
      short8 wl0 = *(const short8*)(WL + wiA);
      short8 wh1 = *(const short8*)(WH + wiA + 3584);
      short8 wl1 = *(const short8*)(WL + wiA + 3584);
      MIXU(gathY(myY0, nlo, khi), gathY(myY0, 16+nlo, khi), oA00, oA01, oA10, oA11);
      MIXU(gathY(myY1, nlo, khi), gathY(myY1, 16+nlo, khi), oB00, oB01, oB10, oB11);
    }
    bpv = bpn;
  }

  #pragma unroll
  for(int u=0;u<2;u++){
    size_t cb = u ? cb1 : cb0;
    #pragma unroll
    for(int ot=0;ot<2;ot++)
      #pragma unroll
      for(int nf=0;nf<2;nf++)
        #pragma unroll
        for(int rr=0;rr<4;rr++){
          f32x4 ov = u==0 ? (ot==0 ? (nf==0?oA00:oA01) : (nf==0?oA10:oA11))
                          : (ot==0 ? (nf==0?oB00:oB01) : (nf==0?oB10:oB11));
          int o = ot*16 + khi*4 + rr;
          int n = (ch*8 + wave*2 + nf)*16 + nlo;
          float val = ov[rr] + bm[o];
          size_t a = cb + (size_t)o*256 + n;
          u16 hh = f2bf(val);
          mbh[a] = hh;
          mbl[a] = f2bf(val - bf2f(hh));
        }
  }
}
#undef LBP
#undef AFU
#undef STEP
#undef MIXU

// ================ k_fuse: round-9 proven version (2048 blocks, barrier-free) ================
#define LB(KS,FC) (*(const short8*)(bp + ((((KS)*16) + cg0 + (FC))<<9) + (lane<<3)))
#define AF(MFI,KS) (*(const short8*)&lA[(MFI*16 + nlo)*256 + (((KS*4+khi)&16)|(((KS*4+khi)&15)^((MFI*16+nlo)&15)))*8])
template<int MODE>
__global__ __launch_bounds__(256, 5) void k_fuse(const u16* __restrict__ X,
                                                 const u16* __restrict__ bpack,
                                                 const u16* __restrict__ WH, const u16* __restrict__ WL,
                                                 const float* __restrict__ bm,
                                                 float* __restrict__ m, u16* __restrict__ mbh, u16* __restrict__ mbl){
  __shared__ __align__(16) u16 lA[8192];
  __shared__ __align__(16) char lYT[9216];
  int tid = threadIdx.x, bid = blockIdx.x;
  int ch = bid & 1;
  size_t cbase = (size_t)(bid >> 1) * 8192;
  const char* Xb = (const char*)(X + cbase);
  #pragma unroll
  for(int i=0;i<4;i++){
    int off = i*4096 + tid*16;
    int row = off >> 9;
    int P = (off >> 4) & 31;
    int L = (P & 16) | ((P & 15) ^ (row & 15));
    short8 v = *(const short8*)(Xb + (size_t)row*512 + L*16);
    *(short8*)((char*)lA + off) = v;
  }
  __syncthreads();
  int lane = tid & 63, wave = tid >> 6;
  int nlo = lane & 15, khi = lane >> 4;
  int cg0 = ch*8 + wave*2;
  char* myY = lYT + wave*2304;

  f32x4 out00={0,0,0,0}, out01=out00, out10=out00, out11=out00;

  {
    int wiA = nlo*224 + khi*8;
    short8 wh0 = *(const short8*)(WH + wiA);
    short8 wl0 = *(const short8*)(WL + wiA);
    short8 wh1 = *(const short8*)(WH + wiA + 3584);
    short8 wl1 = *(const short8*)(WL + wiA + 3584);
    #pragma unroll
    for(int nf=0;nf<2;nf++){
      int n = (ch*8 + wave*2 + nf)*16 + nlo;
      short8 f = gathA((const u16*)lA, n, khi);
      if(nf==0){ out00=MF(wh0,f,out00); out00=MF(wl0,f,out00); out10=MF(wh1,f,out10); out10=MF(wl1,f,out10); }
      else     { out01=MF(wh0,f,out01); out01=MF(wl0,f,out01); out11=MF(wh1,f,out11); out11=MF(wl1,f,out11); }
    }
  }

  #pragma unroll
  for(int v=0; v<6; v++){
    const u16* bp = bpack + ((size_t)v << 16);
    f32x4 h00={0,0,0,0}, h01=h00, h10=h00, h11=h00;
    short8 p0 = LB(0,0), p1 = LB(0,1);
    short8 q0 = LB(1,0), q1 = LB(1,1);
    #pragma unroll
    for(int ks=0; ks<8; ks++){
      short8 r0, r1;
      if(ks < 6){ r0 = LB(ks+2,0); r1 = LB(ks+2,1); }
      short8 a0 = AF(0,ks), a1 = AF(1,ks);
      h00 = MF(a0, p0, h00);
      h01 = MF(a0, p1, h01);
      h10 = MF(a1, p0, h10);
      h11 = MF(a1, p1, h11);
      p0 = q0; p1 = q1;
      if(ks < 6){ q0 = r0; q1 = r1; }
    }
    #pragma unroll
    for(int mf=0;mf<2;mf++)
      #pragma unroll
      for(int nf=0;nf<2;nf++){
        f32x4 hv = mf==0 ? (nf==0?h00:h01) : (nf==0?h10:h11);
        short4a wv;
        wv[0] = (short)f2bf(hv[0]); wv[1] = (short)f2bf(hv[1]);
        wv[2] = (short)f2bf(hv[2]); wv[3] = (short)f2bf(hv[3]);
        *(short4a*)(myY + (nf*16+nlo)*72 + mf*32 + khi*8) = wv;
      }
    {
      int wiA = nlo*224 + (v+1)*32 + khi*8;
      short8 wh0 = *(const short8*)(WH + wiA);
      short8 wl0 = *(const short8*)(WL + wiA);
      short8 wh1 = *(const short8*)(WH + wiA + 3584);
      short8 wl1 = *(const short8*)(WL + wiA + 3584);
      #pragma unroll
      for(int nf=0;nf<2;nf++){
        short8 f = gathY(myY, nf*16+nlo, khi);
        if(nf==0){ out00=MF(wh0,f,out00); out00=MF(wl0,f,out00); out10=MF(wh1,f,out10); out10=MF(wl1,f,out10); }
        else     { out01=MF(wh0,f,out01); out01=MF(wl0,f,out01); out11=MF(wh1,f,out11); out11=MF(wl1,f,out11); }
      }
    }
  }

  #pragma unroll
  for(int ot=0;ot<2;ot++)
    #pragma unroll
    for(int nf=0;nf<2;nf++)
      #pragma unroll
      for(int rr=0;rr<4;rr++){
        f32x4 ov = ot==0 ? (nf==0?out00:out01) : (nf==0?out10:out11);
        int o = ot*16 + khi*4 + rr;
        int n = (ch*8 + wave*2 + nf)*16 + nlo;
        float val = ov[rr] + bm[o];
        size_t a = cbase + (size_t)o*256 + n;
        if(MODE==0){
          u16 hh = f2bf(val);
          mbh[a] = hh;
          mbl[a] = f2bf(val - bf2f(hh));
        } else {
          m[a] = val;
        }
      }
}
#undef LB
#undef AF

// ---------------- m [b][t][o][n] f32 -> dst [b][o][n][t] f32
__global__ __launch_bounds__(256) void k_tip(const float* __restrict__ m, float* __restrict__ dst){
  int tile = blockIdx.x & 15; int slice = blockIdx.x >> 4;
  int b = slice >> 5, o = slice & 31;
  int tn0 = (tile & 3) * 64, tt0 = (tile >> 2) * 64;
  __shared__ float l[64][65];
  int cc = threadIdx.x & 63, r0 = threadIdx.x >> 6;
  #pragma unroll
  for(int k=0;k<16;k++){ int r = r0 + 4*k;
    l[r][cc] = m[(((size_t)b*256 + (tt0+r))*32 + o)*256 + tn0 + cc];
  }
  __syncthreads();
  #pragma unroll
  for(int k=0;k<16;k++){ int r = r0 + 4*k;
    dst[(((size_t)b*32 + o)*256 + (tn0+r))*256 + tt0 + cc] = l[cc][r];
  }
}

extern "C" void kernel_launch(void* const* d_in, const int* in_sizes, int n_in,
                              void* d_out, int out_size, void* d_ws, size_t ws_size,
                              hipStream_t stream){
  (void)in_sizes; (void)n_in; (void)out_size;
  const float* x    = (const float*)d_in[0];
  const float* nv1  = (const float*)d_in[1];
  const float* nv2  = (const float*)d_in[2];
  const float* sup0 = (const float*)d_in[3];
  const float* sup1 = (const float*)d_in[4];
  const float* wf1 = (const float*)d_in[5];  const float* bf1v = (const float*)d_in[6];
  const float* wg1 = (const float*)d_in[7];  const float* bg1v = (const float*)d_in[8];
  const float* wf2 = (const float*)d_in[9];  const float* bf2v = (const float*)d_in[10];
  const float* wg2 = (const float*)d_in[11]; const float* bg2v = (const float*)d_in[12];
  const float* wm1 = (const float*)d_in[13]; const float* bm1 = (const float*)d_in[14];
  const float* wm2 = (const float*)d_in[15]; const float* bm2 = (const float*)d_in[16];
  float* out = (float*)d_out;
  char* ws = (char*)d_ws;
  const size_t MB = (size_t)1 << 20;

  u16*  badj  = (u16*)ws;                    // 384 KB
  float* adp  = (float*)(ws + 786432);       // 256 KB
  u16*  whi   = (u16*)(ws + 1048576);        // 28 KB
  u16*  wlo   = (u16*)(ws + 1077248);        // 28 KB
  u16*  wcp   = (u16*)(ws + 1105920);        // 32 KB
  u16*  bpack = (u16*)(ws + 1179648);        // 768 KB, ends < 2 MB

  int tier = (ws_size >= 100*MB) ? 0 : 1;
  u16* h   = (u16*)(ws + 2*MB);
  u16* mbh = (u16*)(ws + 18*MB);
  u16* mbl = (u16*)(ws + 34*MB);
  u16* xT;
  float *m, *tmp = nullptr;
  if(tier==0){
    m  = (float*)(ws + 50*MB);
    xT = (u16*)(ws + 82*MB);
  } else {
    xT = mbh;                 // xT dead before fuse<0> writes mbh
    m  = out;
    tmp = (float*)(ws + 2*MB);
  }

  k_adpw<<<344,256,0,stream>>>(nv1, nv2, adp, wm1, wm2, wf1, wg1, wf2, wg2, whi, wlo, wcp);
  k_badj<<<768,256,0,stream>>>(sup0, sup1, adp, badj, bpack);
  k_asq<<<12,256,0,stream>>>(badj, sup0, sup1, adp, bpack);
  k_tin<<<2048,256,0,stream>>>(x, xT);

  // block 1: NT=2 variant (A/B test of the occupancy-attribute fix)
  k_cv<0><<<1024,256,0,stream>>>(xT, (const u16*)0, wcp, 0, 1, bf1v, bg1v, h);
  k_fuse2<<<1024,256,0,stream>>>(h, bpack, whi, wlo, bm1, mbh, mbl);
  // block 2: round-9 proven version
  k_cv<1><<<1024,256,0,stream>>>(mbh, mbl, wcp, 1, 2, bf2v, bg2v, h);
  k_fuse<1><<<2048,256,0,stream>>>(h, bpack, whi+7168, wlo+7168, bm2, m, (u16*)0, (u16*)0);

  if(tier==0){
    k_tip<<<2048,256,0,stream>>>(m, out);
  } else {
    k_tip<<<2048,256,0,stream>>>(m, tmp);
    (void)hipMemcpyAsync(out, tmp, (size_t)32*MB, hipMemcpyDeviceToDevice, stream);
  }
}

// Round 18
// 187.031 us; speedup vs baseline: 1.2877x; 1.2877x over previous
//
#include <hip/hip_runtime.h>
#include <hip/hip_bf16.h>
#include <stdint.h>

typedef unsigned short u16;
typedef __attribute__((ext_vector_type(8))) short short8;
typedef __attribute__((ext_vector_type(4))) short short4a;
typedef __attribute__((ext_vector_type(4))) float f32x4;

__device__ __forceinline__ float bf2f(u16 b){ union {unsigned u; float f;} v; v.u = ((unsigned)b)<<16; return v.f; }
__device__ __forceinline__ u16 f2bf(float f){ union {unsigned u; float f;} v; v.f = f; unsigned r = v.u + 0x7FFF + ((v.u>>16)&1); return (u16)(r>>16); }

// ---------------- bpack element index for (s, mat, w, v)
__device__ __forceinline__ size_t bpidx(int s, int mat, int w, int v){
  return ((size_t)(((s*2+mat)*8 + (v>>5))*16 + (w>>4)))*512 + (((v>>3)&3)*16 + (w&15))*8 + (v&7);
}

// ---------------- adaptive adjacency (blocks 0..255) + weight prep (blocks 256..343)
__global__ __launch_bounds__(256) void k_adpw(const float* __restrict__ nv1, const float* __restrict__ nv2,
                                              float* __restrict__ adp,
                                              const float* __restrict__ wm1, const float* __restrict__ wm2,
                                              const float* __restrict__ wf1, const float* __restrict__ wg1,
                                              const float* __restrict__ wf2, const float* __restrict__ wg2,
                                              u16* __restrict__ whi, u16* __restrict__ wlo,
                                              u16* __restrict__ wcp){
  int bid = blockIdx.x;
  if(bid < 256){
    int row = bid; int j = threadIdx.x;
    float s = 0.f;
    #pragma unroll
    for(int k=0;k<10;k++) s = fmaf(nv1[row*10+k], nv2[k*256+j], s);
    s = s > 0.f ? s : 0.f;
    float val = (s == 0.f) ? -1e10f : s;
    __shared__ float red[256];
    red[j] = val; __syncthreads();
    for(int off=128; off>0; off>>=1){ if(j<off) red[j] = fmaxf(red[j], red[j+off]); __syncthreads(); }
    float mx = red[0]; __syncthreads();
    float e = __expf(val - mx);
    red[j] = e; __syncthreads();
    for(int off=128; off>0; off>>=1){ if(j<off) red[j] += red[j+off]; __syncthreads(); }
    adp[row*256+j] = e / red[0];
  } else {
    int idx = (bid-256)*256 + threadIdx.x;
    if(idx < 14336){
      float w = (idx < 7168) ? wm1[idx] : wm2[idx-7168];
      u16 hh = f2bf(w);
      whi[idx] = hh;
      wlo[idx] = f2bf(w - bf2f(hh));
    } else if(idx < 22528){
      int e = idx - 14336;
      int blk = e >> 12; int rem = e & 4095;
      int row = rem >> 6; int kk = rem & 63;
      int tap = kk >> 5; int i = kk & 31; int o = row & 31;
      const float* wsrc = blk ? (row<32 ? wf2 : wg2) : (row<32 ? wf1 : wg1);
      float w = wsrc[(o*32+i)*2 + tap];
      u16 hh = f2bf(w);
      wcp[blk*8192 + 0    + rem] = hh;
      wcp[blk*8192 + 4096 + rem] = f2bf(w - bf2f(hh));
    }
  }
}

// ---------------- badj[s][w][v] = src_s[v][w]; also writes bpack mat=0 entries
__global__ __launch_bounds__(256) void k_badj(const float* __restrict__ s0, const float* __restrict__ s1,
                                              const float* __restrict__ adp, u16* __restrict__ badj,
                                              u16* __restrict__ bpack){
  int s = blockIdx.x >> 8; int w = blockIdx.x & 255; int v = threadIdx.x;
  const float* src = s==0 ? s0 : (s==1 ? s1 : adp);
  u16 val = f2bf(src[v*256 + w]);
  badj[(s<<16) + (w<<8) + v] = val;
  bpack[bpidx(s, 0, w, v)] = val;
}

// ---------------- x [b][c][n][t] f32 -> xT [b][t][c][n] bf16
__global__ __launch_bounds__(256) void k_tin(const float* __restrict__ x, u16* __restrict__ xT){
  int tile = blockIdx.x & 15; int slice = blockIdx.x >> 4;
  int b = slice >> 5, c = slice & 31;
  int tn0 = (tile & 3) * 64;
  int tt0 = (tile >> 2) * 64;
  const float* src = x + (size_t)slice*65536;
  __shared__ float l[64][65];
  int cc = threadIdx.x & 63, r0 = threadIdx.x >> 6;
  #pragma unroll
  for(int k=0;k<16;k++){ int r = r0 + 4*k;
    l[r][cc] = src[(size_t)(tn0 + r)*256 + tt0 + cc];
  }
  __syncthreads();
  #pragma unroll
  for(int k=0;k<16;k++){ int r = r0 + 4*k;
    xT[(((size_t)b*256 + (tt0+r))*32 + c)*256 + tn0 + cc] = f2bf(l[cc][r]);
  }
}

// ---------------- A^2: reads badj (staged), writes results DIRECTLY in bpack mat=1 layout
__global__ __launch_bounds__(256) void k_asq(const u16* __restrict__ badj,
                                             const float* __restrict__ s0, const float* __restrict__ s1,
                                             const float* __restrict__ adp, u16* __restrict__ bpack){
  __shared__ __align__(16) u16 lds[16384];
  int tid = threadIdx.x, bid = blockIdx.x;
  int s = bid >> 2, rt = bid & 3;
  int w0 = rt << 6;
  const u16* T = badj + (s<<16);
  const float* S = s==0 ? s0 : (s==1 ? s1 : adp);
  #pragma unroll
  for(int i=0;i<8;i++){
    int off = i*4096 + tid*16;
    int row = off >> 9;
    int P = (off >> 4) & 31;
    int L = (P & 16) | ((P & 15) ^ (row & 15));
    short8 v = *(const short8*)((const char*)T + (size_t)(w0 + row)*512 + L*16);
    *(short8*)((char*)lds + off) = v;
  }
  __syncthreads();
  int lane = tid & 63, wave = tid >> 6;
  int wr = (wave >> 1) << 5, wc = (wave & 1) << 7;
  f32x4 acc[2][8];
  #pragma unroll
  for(int a=0;a<2;a++)
    #pragma unroll
    for(int q=0;q<8;q++) acc[a][q] = {0.f,0.f,0.f,0.f};
  for(int ks=0; ks<8; ks++){
    short8 afr[2], bfr[8];
    #pragma unroll
    for(int mf=0; mf<2; mf++){
      int row = wr + mf*16 + (lane & 15);
      int L = ks*4 + (lane >> 4);
      int P = (L & 16) | ((L & 15) ^ (row & 15));
      afr[mf] = *(const short8*)&lds[row*256 + P*8];
    }
    #pragma unroll
    for(int nf=0; nf<8; nf++){
      int col = wc + nf*16 + (lane & 15);
      const float* src = S + (size_t)col*256 + ks*32 + (lane>>4)*8;
      #pragma unroll
      for(int jj=0;jj<8;jj++) bfr[nf][jj] = (short)f2bf(src[jj]);
    }
    #pragma unroll
    for(int mf=0;mf<2;mf++)
      #pragma unroll
      for(int nf=0;nf<8;nf++)
        acc[mf][nf] = __builtin_amdgcn_mfma_f32_16x16x32_bf16(afr[mf], bfr[nf], acc[mf][nf], 0,0,0);
  }
  #pragma unroll
  for(int mf=0;mf<2;mf++)
    #pragma unroll
    for(int nf=0;nf<8;nf++)
      #pragma unroll
      for(int rr=0;rr<4;rr++){
        int w = w0 + wr + mf*16 + (lane>>4)*4 + rr;
        int v = wc + nf*16 + (lane&15);
        bpack[bpidx(s, 1, w, v)] = f2bf(acc[mf][nf][rr]);
      }
}

// ---------------- MFMA gated conv (+bias, sigmoid gate)
template<int HILO>
__global__ __launch_bounds__(256) void k_cv(const u16* __restrict__ X0, const u16* __restrict__ X1,
                                            const u16* __restrict__ wcp, int blk, int dil,
                                            const float* __restrict__ bfv, const float* __restrict__ bgv,
                                            u16* __restrict__ outh){
  __shared__ __align__(16) u16 pl[(1+HILO)*2*8192];
  const int NPART = 1+HILO;
  int tid = threadIdx.x, bid = blockIdx.x;
  int b = bid >> 8, t = bid & 255;
  size_t base_cur = ((size_t)(b*256 + t))*8192;
  const u16* Xs[2] = {X0, X1};
  #pragma unroll
  for(int part=0; part<NPART; part++){
    #pragma unroll
    for(int tap=0; tap<2; tap++){
      bool valid = (tap==1) || (t >= dil);
      const u16* src = Xs[part] + base_cur - (tap==0 ? (size_t)dil*8192 : 0);
      char* pb = (char*)pl + (tap*NPART + part)*16384;
      #pragma unroll
      for(int it=0; it<4; it++){
        int off = it*4096 + tid*16;
        int c = off >> 9;
        int byte = off & 511;
        short8 v = {0,0,0,0,0,0,0,0};
        if(valid) v = *(const short8*)(src + (off>>1));
        *(short8*)(pb + c*512 + (byte ^ ((c&24)<<2))) = v;
      }
    }
  }
  int lane = tid & 63, wave = tid >> 6;
  const u16* wb = wcp + blk*8192;
  short8 wfr[4][2][2];
  #pragma unroll
  for(int ot=0;ot<4;ot++)
    #pragma unroll
    for(int ks=0;ks<2;ks++)
      #pragma unroll
      for(int p=0;p<2;p++)
        wfr[ot][ks][p] = *(const short8*)(wb + p*4096 + (ot*16 + (lane&15))*64 + ks*32 + (lane>>4)*8);
  __syncthreads();

  f32x4 acc[4][4];
  #pragma unroll
  for(int a=0;a<4;a++)
    #pragma unroll
    for(int q=0;q<4;q++) acc[a][q] = {0.f,0.f,0.f,0.f};
  int nbase = wave << 6;
  #pragma unroll
  for(int nf=0; nf<4; nf++){
    int n = nbase + nf*16 + (lane & 15);
    #pragma unroll
    for(int ks=0; ks<2; ks++){
      short8 xv[NPART];
      #pragma unroll
      for(int p=0;p<NPART;p++){
        char* pb = (char*)pl + (ks*NPART + p)*16384;
        short8 v;
        #pragma unroll
        for(int jj=0;jj<8;jj++){
          int c = ((lane>>4)<<3) + jj;
          v[jj] = *(const short*)(pb + c*512 + ((n*2) ^ ((c&24)<<2)));
        }
        xv[p] = v;
      }
      #pragma unroll
      for(int ot=0; ot<4; ot++){
        acc[ot][nf] = __builtin_amdgcn_mfma_f32_16x16x32_bf16(wfr[ot][ks][0], xv[0], acc[ot][nf], 0,0,0);
        acc[ot][nf] = __builtin_amdgcn_mfma_f32_16x16x32_bf16(wfr[ot][ks][1], xv[0], acc[ot][nf], 0,0,0);
        if(HILO)
          acc[ot][nf] = __builtin_amdgcn_mfma_f32_16x16x32_bf16(wfr[ot][ks][0], xv[HILO], acc[ot][nf], 0,0,0);
      }
    }
  }
  u16* ob = outh + base_cur;
  #pragma unroll
  for(int ot=0; ot<2; ot++)
    #pragma unroll
    for(int nf=0; nf<4; nf++)
      #pragma unroll
      for(int rr=0; rr<4; rr++){
        int o = ot*16 + (lane>>4)*4 + rr;
        int n = nbase + nf*16 + (lane&15);
        float fv = acc[ot][nf][rr] + bfv[o];
        float gv = acc[ot+2][nf][rr] + bgv[o];
        ob[(size_t)o*256 + n] = f2bf(fv / (1.f + __expf(-gv)));
      }
}

// ---------------- gather helpers
__device__ __forceinline__ short8 gathA(const u16* TB, int n, int khi){
  short8 f; int Lc = n >> 3; int bb = (n & 7)*2;
  #pragma unroll
  for(int j=0;j<8;j++){
    int c = khi*8 + j;
    int P = (Lc & 16) | ((Lc & 15) ^ (c & 15));
    f[j] = (short)*(const u16*)((const char*)TB + c*512 + P*16 + bb);
  }
  return f;
}
__device__ __forceinline__ short8 gathY(const char* myY, int nl, int khi){
  const char* rp = myY + nl*72 + khi*16;
  short4a g0 = *(const short4a*)rp;
  short4a g1 = *(const short4a*)(rp + 8);
  return (short8){g0[0],g0[1],g0[2],g0[3],g1[0],g1[1],g1[2],g1[3]};
}

#define MF(A,B,C) __builtin_amdgcn_mfma_f32_16x16x32_bf16((A),(B),(C),0,0,0)

// ================ k_fuse: round-9 proven version (2048 blocks, barrier-free) ================
#define LB(KS,FC) (*(const short8*)(bp + ((((KS)*16) + cg0 + (FC))<<9) + (lane<<3)))
#define AF(MFI,KS) (*(const short8*)&lA[(MFI*16 + nlo)*256 + (((KS*4+khi)&16)|(((KS*4+khi)&15)^((MFI*16+nlo)&15)))*8])
template<int MODE>
__global__ __launch_bounds__(256, 5) void k_fuse(const u16* __restrict__ X,
                                                 const u16* __restrict__ bpack,
                                                 const u16* __restrict__ WH, const u16* __restrict__ WL,
                                                 const float* __restrict__ bm,
                                                 float* __restrict__ m, u16* __restrict__ mbh, u16* __restrict__ mbl){
  __shared__ __align__(16) u16 lA[8192];
  __shared__ __align__(16) char lYT[9216];
  int tid = threadIdx.x, bid = blockIdx.x;
  int ch = bid & 1;
  size_t cbase = (size_t)(bid >> 1) * 8192;
  const char* Xb = (const char*)(X + cbase);
  #pragma unroll
  for(int i=0;i<4;i++){
    int off = i*4096 + tid*16;
    int row = off >> 9;
    int P = (off >> 4) & 31;
    int L = (P & 16) | ((P & 15) ^ (row & 15));
    short8 v = *(const short8*)(Xb + (size_t)row*512 + L*16);
    *(short8*)((char*)lA + off) = v;
  }
  __syncthreads();
  int lane = tid & 63, wave = tid >> 6;
  int nlo = lane & 15, khi = lane >> 4;
  int cg0 = ch*8 + wave*2;
  char* myY = lYT + wave*2304;

  f32x4 out00={0,0,0,0}, out01=out00, out10=out00, out11=out00;

  {
    int wiA = nlo*224 + khi*8;
    short8 wh0 = *(const short8*)(WH + wiA);
    short8 wl0 = *(const short8*)(WL + wiA);
    short8 wh1 = *(const short8*)(WH + wiA + 3584);
    short8 wl1 = *(const short8*)(WL + wiA + 3584);
    #pragma unroll
    for(int nf=0;nf<2;nf++){
      int n = (ch*8 + wave*2 + nf)*16 + nlo;
      short8 f = gathA((const u16*)lA, n, khi);
      if(nf==0){ out00=MF(wh0,f,out00); out00=MF(wl0,f,out00); out10=MF(wh1,f,out10); out10=MF(wl1,f,out10); }
      else     { out01=MF(wh0,f,out01); out01=MF(wl0,f,out01); out11=MF(wh1,f,out11); out11=MF(wl1,f,out11); }
    }
  }

  #pragma unroll
  for(int v=0; v<6; v++){
    const u16* bp = bpack + ((size_t)v << 16);
    f32x4 h00={0,0,0,0}, h01=h00, h10=h00, h11=h00;
    short8 p0 = LB(0,0), p1 = LB(0,1);
    short8 q0 = LB(1,0), q1 = LB(1,1);
    #pragma unroll
    for(int ks=0; ks<8; ks++){
      short8 r0, r1;
      if(ks < 6){ r0 = LB(ks+2,0); r1 = LB(ks+2,1); }
      short8 a0 = AF(0,ks), a1 = AF(1,ks);
      h00 = MF(a0, p0, h00);
      h01 = MF(a0, p1, h01);
      h10 = MF(a1, p0, h10);
      h11 = MF(a1, p1, h11);
      p0 = q0; p1 = q1;
      if(ks < 6){ q0 = r0; q1 = r1; }
    }
    #pragma unroll
    for(int mf=0;mf<2;mf++)
      #pragma unroll
      for(int nf=0;nf<2;nf++){
        f32x4 hv = mf==0 ? (nf==0?h00:h01) : (nf==0?h10:h11);
        short4a wv;
        wv[0] = (short)f2bf(hv[0]); wv[1] = (short)f2bf(hv[1]);
        wv[2] = (short)f2bf(hv[2]); wv[3] = (short)f2bf(hv[3]);
        *(short4a*)(myY + (nf*16+nlo)*72 + mf*32 + khi*8) = wv;
      }
    {
      int wiA = nlo*224 + (v+1)*32 + khi*8;
      short8 wh0 = *(const short8*)(WH + wiA);
      short8 wl0 = *(const short8*)(WL + wiA);
      short8 wh1 = *(const short8*)(WH + wiA + 3584);
      short8 wl1 = *(const short8*)(WL + wiA + 3584);
      #pragma unroll
      for(int nf=0;nf<2;nf++){
        short8 f = gathY(myY, nf*16+nlo, khi);
        if(nf==0){ out00=MF(wh0,f,out00); out00=MF(wl0,f,out00); out10=MF(wh1,f,out10); out10=MF(wl1,f,out10); }
        else     { out01=MF(wh0,f,out01); out01=MF(wl0,f,out01); out11=MF(wh1,f,out11); out11=MF(wl1,f,out11); }
      }
    }
  }

  #pragma unroll
  for(int ot=0;ot<2;ot++)
    #pragma unroll
    for(int nf=0;nf<2;nf++)
      #pragma unroll
      for(int rr=0;rr<4;rr++){
        f32x4 ov = ot==0 ? (nf==0?out00:out01) : (nf==0?out10:out11);
        int o = ot*16 + khi*4 + rr;
        int n = (ch*8 + wave*2 + nf)*16 + nlo;
        float val = ov[rr] + bm[o];
        size_t a = cbase + (size_t)o*256 + n;
        if(MODE==0){
          u16 hh = f2bf(val);
          mbh[a] = hh;
          mbl[a] = f2bf(val - bf2f(hh));
        } else {
          m[a] = val;
        }
      }
}
#undef LB
#undef AF

// ---------------- m [b][t][o][n] f32 -> dst [b][o][n][t] f32
__global__ __launch_bounds__(256) void k_tip(const float* __restrict__ m, float* __restrict__ dst){
  int tile = blockIdx.x & 15; int slice = blockIdx.x >> 4;
  int b = slice >> 5, o = slice & 31;
  int tn0 = (tile & 3) * 64, tt0 = (tile >> 2) * 64;
  __shared__ float l[64][65];
  int cc = threadIdx.x & 63, r0 = threadIdx.x >> 6;
  #pragma unroll
  for(int k=0;k<16;k++){ int r = r0 + 4*k;
    l[r][cc] = m[(((size_t)b*256 + (tt0+r))*32 + o)*256 + tn0 + cc];
  }
  __syncthreads();
  #pragma unroll
  for(int k=0;k<16;k++){ int r = r0 + 4*k;
    dst[(((size_t)b*32 + o)*256 + (tn0+r))*256 + tt0 + cc] = l[cc][r];
  }
}

extern "C" void kernel_launch(void* const* d_in, const int* in_sizes, int n_in,
                              void* d_out, int out_size, void* d_ws, size_t ws_size,
                              hipStream_t stream){
  (void)in_sizes; (void)n_in; (void)out_size;
  const float* x    = (const float*)d_in[0];
  const float* nv1  = (const float*)d_in[1];
  const float* nv2  = (const float*)d_in[2];
  const float* sup0 = (const float*)d_in[3];
  const float* sup1 = (const float*)d_in[4];
  const float* wf1 = (const float*)d_in[5];  const float* bf1v = (const float*)d_in[6];
  const float* wg1 = (const float*)d_in[7];  const float* bg1v = (const float*)d_in[8];
  const float* wf2 = (const float*)d_in[9];  const float* bf2v = (const float*)d_in[10];
  const float* wg2 = (const float*)d_in[11]; const float* bg2v = (const float*)d_in[12];
  const float* wm1 = (const float*)d_in[13]; const float* bm1 = (const float*)d_in[14];
  const float* wm2 = (const float*)d_in[15]; const float* bm2 = (const float*)d_in[16];
  float* out = (float*)d_out;
  char* ws = (char*)d_ws;
  const size_t MB = (size_t)1 << 20;

  u16*  badj  = (u16*)ws;                    // 384 KB
  float* adp  = (float*)(ws + 786432);       // 256 KB
  u16*  whi   = (u16*)(ws + 1048576);        // 28 KB
  u16*  wlo   = (u16*)(ws + 1077248);        // 28 KB
  u16*  wcp   = (u16*)(ws + 1105920);        // 32 KB
  u16*  bpack = (u16*)(ws + 1179648);        // 768 KB, ends < 2 MB

  int tier = (ws_size >= 100*MB) ? 0 : 1;
  u16* h   = (u16*)(ws + 2*MB);
  u16* mbh = (u16*)(ws + 18*MB);
  u16* mbl = (u16*)(ws + 34*MB);
  u16* xT;
  float *m, *tmp = nullptr;
  if(tier==0){
    m  = (float*)(ws + 50*MB);
    xT = (u16*)(ws + 82*MB);
  } else {
    xT = mbh;                 // xT dead before fuse<0> writes mbh
    m  = out;
    tmp = (float*)(ws + 2*MB);
  }

  k_adpw<<<344,256,0,stream>>>(nv1, nv2, adp, wm1, wm2, wf1, wg1, wf2, wg2, whi, wlo, wcp);
  k_badj<<<768,256,0,stream>>>(sup0, sup1, adp, badj, bpack);
  k_asq<<<12,256,0,stream>>>(badj, sup0, sup1, adp, bpack);
  k_tin<<<2048,256,0,stream>>>(x, xT);

  // block 1
  k_cv<0><<<1024,256,0,stream>>>(xT, (const u16*)0, wcp, 0, 1, bf1v, bg1v, h);
  k_fuse<0><<<2048,256,0,stream>>>(h, bpack, whi, wlo, bm1, (float*)0, mbh, mbl);
  // block 2
  k_cv<1><<<1024,256,0,stream>>>(mbh, mbl, wcp, 1, 2, bf2v, bg2v, h);
  k_fuse<1><<<2048,256,0,stream>>>(h, bpack, whi+7168, wlo+7168, bm2, m, (u16*)0, (u16*)0);

  if(tier==0){
    k_tip<<<2048,256,0,stream>>>(m, out);
  } else {
    k_tip<<<2048,256,0,stream>>>(m, tmp);
    (void)hipMemcpyAsync(out, tmp, (size_t)32*MB, hipMemcpyDeviceToDevice, stream);
  }
}